// Round 7
// baseline (370.132 us; speedup 1.0000x reference)
//
#include <hip/hip_runtime.h>
#include <hip/hip_fp16.h>
#include <math.h>

// PDELayer: 100 steps of u <- u + alpha(row)*u_xx + beta(col)*u_yy, 48x48
// interior with a FROZEN reflect-pad ring.
//
// R7: refit of R1-R6 counters shows VALUBusy is CU-level (any-of-4-SIMD);
// per-SIMD issue util was only 32% at 4 waves/SIMD (R5/R6) vs 42-57% at 8
// (R1/R4) -> latency-bound. This round keeps the f16x2 packing but packs
// TWO HALVES OF THE SAME IMAGE per lane (rows 6ty+k in .lo, rows 47-6ty-k
// reversed in .hi) so one wave = one image -> 8192 waves = 8/SIMD.
// The reversed fold makes the row-23/24 seam self-neighboring (16-bit
// rotate of the lane's own reg) and ty==0's halo entirely frozen pad.
// bpermutes issued at step start, consumed last (rows 1..5 then 0) ->
// LDS latency hidden. No LDS, no barriers, single dispatch.

#define NTSTEPS 100

typedef __half2 h2;

__device__ __forceinline__ h2 dpp_row_shr1(h2 oldv, h2 x) {
    // lane tx receives lane tx-1 within its 16-lane row; tx==0 keeps oldv
    int r = __builtin_amdgcn_update_dpp(
        __builtin_bit_cast(int, oldv), __builtin_bit_cast(int, x),
        0x111, 0xF, 0xF, false);
    return __builtin_bit_cast(h2, r);
}
__device__ __forceinline__ h2 dpp_row_shl1(h2 oldv, h2 x) {
    // lane tx receives lane tx+1 within its 16-lane row; tx==15 keeps oldv
    int r = __builtin_amdgcn_update_dpp(
        __builtin_bit_cast(int, oldv), __builtin_bit_cast(int, x),
        0x101, 0xF, 0xF, false);
    return __builtin_bit_cast(h2, r);
}
__device__ __forceinline__ h2 bperm(int addr, h2 x) {
    int r = __builtin_amdgcn_ds_bpermute(addr, __builtin_bit_cast(int, x));
    return __builtin_bit_cast(h2, r);
}
__device__ __forceinline__ h2 swap16(h2 x) {
    unsigned int v = __builtin_bit_cast(unsigned int, x);
    return __builtin_bit_cast(h2, (v >> 16) | (v << 16));
}

__global__ __launch_bounds__(256, 8) void pde_kernel(
    const float* __restrict__ u0,
    const float* __restrict__ pa1, const float* __restrict__ pa2,
    const float* __restrict__ pa3, const float* __restrict__ pb1,
    const float* __restrict__ pb2, const float* __restrict__ pb3,
    float* __restrict__ out)
{
    const int tid  = threadIdx.x;
    const int lane = tid & 63;
    const int wv   = tid >> 6;
    const int img  = blockIdx.x * 4 + wv;   // one image per wave
    const int tx   = lane & 15;
    const int ty   = lane >> 4;
    const int c0   = 3 * tx;     // first col owned
    const int rlo0 = 6 * ty;     // .lo rows: rlo0..rlo0+5 ; .hi rows: 47-(..)

    // ---- coefficients (per lane, packed per half) ----
    const float a1 = fabsf(pa1[0]), a2 = fabsf(pa2[0]), a3 = fabsf(pa3[0]);
    const float b1 = fabsf(pb1[0]), b2 = fabsf(pb2[0]), b3 = fabsf(pb3[0]);
    const float C = 6.283185307179586f / 47.0f;
    h2 a[6], b[3];
    #pragma unroll
    for (int k = 0; k < 6; ++k) {
        int rl = rlo0 + k, rh = 47 - rl;
        float alo = 0.1152f * (a1 + a2 * sinf(C * rl) + a3 * cosf(C * rl));
        float ahi = 0.1152f * (a1 + a2 * sinf(C * rh) + a3 * cosf(C * rh));
        a[k] = __floats2half2_rn(alo, ahi);
    }
    #pragma unroll
    for (int c = 0; c < 3; ++c) {
        int col = c0 + c;
        float bb = 0.2304f * (b1 + b2 * cosf(C * col) + b3 * sinf(C * col));
        b[c] = __half2half2(__float2half(bb));
    }
    const h2 neg2 = __floats2half2_rn(-2.0f, -2.0f);

    // ---- state + frozen pads ----
    const float* __restrict__ src = u0 + (size_t)img * 2304;
    h2 u[6][3];       // {row rlo0+k, row 47-rlo0-k} x 3 cols
    h2 ep[6];         // horizontal pad: {col1|col46 values} for both rows
    h2 padV[3];       // {init row1, init row46} per col (used by ty==0 halo)

    const int epc = (tx == 15) ? 46 : 1;
    #pragma unroll
    for (int k = 0; k < 6; ++k) {
        int rl = rlo0 + k, rh = 47 - rl;
        #pragma unroll
        for (int c = 0; c < 3; ++c)
            u[k][c] = __floats2half2_rn(src[rl * 48 + c0 + c],
                                        src[rh * 48 + c0 + c]);
        ep[k] = __floats2half2_rn(src[rl * 48 + epc], src[rh * 48 + epc]);
    }
    #pragma unroll
    for (int c = 0; c < 3; ++c)
        padV[c] = __floats2half2_rn(src[48 + c0 + c], src[46 * 48 + c0 + c]);

    const int upA = ((lane - 16) & 63) << 2;
    const int dnA = ((lane + 16) & 63) << 2;
    const bool top = (ty == 0);
    const bool bot = (ty == 3);

    #pragma unroll 1
    for (int t = 0; t < NTSTEPS; ++t) {
        // vertical halo exchange (issued first, consumed last -> hidden)
        h2 wT0 = bperm(upA, u[5][0]);
        h2 wT1 = bperm(upA, u[5][1]);
        h2 wT2 = bperm(upA, u[5][2]);
        h2 wB0 = bperm(dnA, u[0][0]);
        h2 wB1 = bperm(dnA, u[0][1]);
        h2 wB2 = bperm(dnA, u[0][2]);

        // save old u[1] (k=0 computed last needs it) and old u[0] (up of k=1)
        h2 o1_0 = u[1][0], o1_1 = u[1][1], o1_2 = u[1][2];
        h2 p0 = u[0][0], p1 = u[0][1], p2 = u[0][2];

        // interior rows k = 1..4 (all operands in-register, old values)
        #pragma unroll
        for (int k = 1; k <= 4; ++k) {
            const h2 x0 = u[k][0], x1 = u[k][1], x2 = u[k][2];
            const h2 hl = dpp_row_shr1(ep[k], x2);
            const h2 hr = dpp_row_shl1(ep[k], x0);
            const h2 d0 = u[k + 1][0], d1 = u[k + 1][1], d2 = u[k + 1][2];
            const h2 v0 = __hadd2(p0, d0), v1 = __hadd2(p1, d1), v2 = __hadd2(p2, d2);
            const h2 g0 = __hadd2(hl, x1), g1 = __hadd2(x0, x2), g2 = __hadd2(x1, hr);
            const h2 t10 = __hfma2(neg2, x0, v0), t11 = __hfma2(neg2, x1, v1), t12 = __hfma2(neg2, x2, v2);
            const h2 t20 = __hfma2(neg2, x0, g0), t21 = __hfma2(neg2, x1, g1), t22 = __hfma2(neg2, x2, g2);
            u[k][0] = __hfma2(b[0], t20, __hfma2(a[k], t10, x0));
            u[k][1] = __hfma2(b[1], t21, __hfma2(a[k], t11, x1));
            u[k][2] = __hfma2(b[2], t22, __hfma2(a[k], t12, x2));
            p0 = x0; p1 = x1; p2 = x2;
        }

        // k = 5: down-neighbor = seam (own swapped reg for ty==3) or wrapB
        {
            const h2 x0 = u[5][0], x1 = u[5][1], x2 = u[5][2];
            const h2 bh0 = bot ? swap16(x0) : wB0;
            const h2 bh1 = bot ? swap16(x1) : wB1;
            const h2 bh2 = bot ? swap16(x2) : wB2;
            const h2 hl = dpp_row_shr1(ep[5], x2);
            const h2 hr = dpp_row_shl1(ep[5], x0);
            const h2 v0 = __hadd2(p0, bh0), v1 = __hadd2(p1, bh1), v2 = __hadd2(p2, bh2);
            const h2 g0 = __hadd2(hl, x1), g1 = __hadd2(x0, x2), g2 = __hadd2(x1, hr);
            const h2 t10 = __hfma2(neg2, x0, v0), t11 = __hfma2(neg2, x1, v1), t12 = __hfma2(neg2, x2, v2);
            const h2 t20 = __hfma2(neg2, x0, g0), t21 = __hfma2(neg2, x1, g1), t22 = __hfma2(neg2, x2, g2);
            u[5][0] = __hfma2(b[0], t20, __hfma2(a[5], t10, x0));
            u[5][1] = __hfma2(b[1], t21, __hfma2(a[5], t11, x1));
            u[5][2] = __hfma2(b[2], t22, __hfma2(a[5], t12, x2));
        }

        // k = 0: up-neighbor = frozen pads (ty==0) or wrapT; down = old u[1]
        {
            const h2 x0 = u[0][0], x1 = u[0][1], x2 = u[0][2];
            const h2 th0 = top ? padV[0] : wT0;
            const h2 th1 = top ? padV[1] : wT1;
            const h2 th2 = top ? padV[2] : wT2;
            const h2 hl = dpp_row_shr1(ep[0], x2);
            const h2 hr = dpp_row_shl1(ep[0], x0);
            const h2 v0 = __hadd2(th0, o1_0), v1 = __hadd2(th1, o1_1), v2 = __hadd2(th2, o1_2);
            const h2 g0 = __hadd2(hl, x1), g1 = __hadd2(x0, x2), g2 = __hadd2(x1, hr);
            const h2 t10 = __hfma2(neg2, x0, v0), t11 = __hfma2(neg2, x1, v1), t12 = __hfma2(neg2, x2, v2);
            const h2 t20 = __hfma2(neg2, x0, g0), t21 = __hfma2(neg2, x1, g1), t22 = __hfma2(neg2, x2, g2);
            u[0][0] = __hfma2(b[0], t20, __hfma2(a[0], t10, x0));
            u[0][1] = __hfma2(b[1], t21, __hfma2(a[0], t11, x1));
            u[0][2] = __hfma2(b[2], t22, __hfma2(a[0], t12, x2));
        }
    }

    // ---- epilogue: unpack both halves to fp32 ----
    float* __restrict__ dst = out + (size_t)img * 2304;
    #pragma unroll
    for (int k = 0; k < 6; ++k) {
        int rl = rlo0 + k, rh = 47 - rl;
        #pragma unroll
        for (int c = 0; c < 3; ++c) {
            dst[rl * 48 + c0 + c] = __low2float(u[k][c]);
            dst[rh * 48 + c0 + c] = __high2float(u[k][c]);
        }
    }
}

extern "C" void kernel_launch(void* const* d_in, const int* in_sizes, int n_in,
                              void* d_out, int out_size, void* d_ws, size_t ws_size,
                              hipStream_t stream) {
    const float* u0 = (const float*)d_in[0];
    pde_kernel<<<2048, 256, 0, stream>>>(
        u0,
        (const float*)d_in[1], (const float*)d_in[2], (const float*)d_in[3],
        (const float*)d_in[4], (const float*)d_in[5], (const float*)d_in[6],
        (float*)d_out);
}